// Round 3
// baseline (1428.510 us; speedup 1.0000x reference)
//
#include <hip/hip_runtime.h>
#include <hip/hip_bf16.h>
#include <stdint.h>

typedef __attribute__((ext_vector_type(4))) float f32x4;
typedef __attribute__((ext_vector_type(8))) short bf16x8;
typedef __attribute__((ext_vector_type(4))) unsigned short u16x4;

static __device__ __forceinline__ unsigned short f2bf(float f) {
    __hip_bfloat16 h = __float2bfloat16(f);
    return *reinterpret_cast<unsigned short*>(&h);
}

static __device__ __forceinline__ void gload_lds16(const void* g, void* l) {
    __builtin_amdgcn_global_load_lds(
        (const __attribute__((address_space(1))) unsigned int*)(uintptr_t)g,
        (__attribute__((address_space(3))) unsigned int*)(uintptr_t)l,
        16, 0, 0);
}

// ---------------------------------------------------------------------------
// w[e] = edge_features[e,:] . p[:]
__global__ void calc_w(const float* __restrict__ ef, const float* __restrict__ p,
                       float* __restrict__ w, int E) {
    int e = blockIdx.x * 256 + threadIdx.x;
    if (e < E) w[e] = ef[3*e] * p[0] + ef[3*e+1] * p[1] + ef[3*e+2] * p[2];
}

// A = bf16(T * w[col]), B = bf16(T)   (float4-vectorized, grid-stride)
// emask: E-1 when E is a power of two (avoids integer division in the hot loop)
__global__ void conv_T(const float* __restrict__ T, const float* __restrict__ wbuf,
                       __hip_bfloat16* __restrict__ Aw, __hip_bfloat16* __restrict__ Bt,
                       size_t total4, int E, unsigned int emask) {
    size_t i = (size_t)blockIdx.x * blockDim.x + threadIdx.x;
    size_t stride = (size_t)gridDim.x * blockDim.x;
    for (; i < total4; i += stride) {
        size_t base = i * 4;
        float4 t = reinterpret_cast<const float4*>(T)[i];
        int c = (emask != 0xFFFFFFFFu) ? (int)(base & (size_t)emask)
                                       : (int)(base % (size_t)E);
        float w0 = wbuf[c], w1 = wbuf[c+1], w2 = wbuf[c+2], w3 = wbuf[c+3];
        u16x4 b, a;
        b[0] = f2bf(t.x); b[1] = f2bf(t.y); b[2] = f2bf(t.z); b[3] = f2bf(t.w);
        a[0] = f2bf(t.x * w0); a[1] = f2bf(t.y * w1); a[2] = f2bf(t.z * w2); a[3] = f2bf(t.w * w3);
        reinterpret_cast<u16x4*>(Bt)[i] = b;
        reinterpret_cast<u16x4*>(Aw)[i] = a;
    }
}

// plain f32 -> bf16 (float4-vectorized, grid-stride)
__global__ void conv_plain(const float* __restrict__ src, __hip_bfloat16* __restrict__ dst,
                           size_t total4) {
    size_t i = (size_t)blockIdx.x * blockDim.x + threadIdx.x;
    size_t stride = (size_t)gridDim.x * blockDim.x;
    for (; i < total4; i += stride) {
        float4 t = reinterpret_cast<const float4*>(src)[i];
        u16x4 b;
        b[0] = f2bf(t.x); b[1] = f2bf(t.y); b[2] = f2bf(t.z); b[3] = f2bf(t.w);
        reinterpret_cast<u16x4*>(dst)[i] = b;
    }
}

// weight [din][dout] -> Wt bf16 [dout][din] (transposed)
__global__ void conv_Wt(const float* __restrict__ Wsrc, __hip_bfloat16* __restrict__ Wt,
                        int din, int dout) {
    int idx = blockIdx.x * 256 + threadIdx.x;
    if (idx < din * dout) {
        int i = idx / dout, j = idx % dout;
        Wt[(size_t)j * din + i] = __float2bfloat16(Wsrc[idx]);
    }
}

// ---------------------------------------------------------------------------
// C[M][Ng] = A[M][K] @ B[Ng][K]^T   (both row-major, K contiguous; bf16 in, f32 acc)
// m97 structure: 128x128 tile, BK=64, 4 waves (2x2), 16x16x32 bf16 MFMA,
// global_load_lds width=16, XCD-swizzled blockIdx.
// EPI=1: outB[idx] = bf16( row==col ? adj[idx] : acc*adj[idx] )   (adjusted_A)
// EPI=2: outF[idx] = acc + bias[col]                               (final out)
// EPI=3: outB[col*ldT + row..row+3] = bf16(acc)                    (transposed store)
template <int EPI>
__global__ __launch_bounds__(256)
void gemm_bt(const __hip_bfloat16* __restrict__ A, const __hip_bfloat16* __restrict__ B,
             int M, int Ng, int K,
             const float* __restrict__ adj, float* __restrict__ outF,
             const float* __restrict__ bias, __hip_bfloat16* __restrict__ outB, int ldT) {
    constexpr int BM = 128, BN = 128, BK = 64;
    __shared__ __align__(16) __hip_bfloat16 As[BM * BK];
    __shared__ __align__(16) __hip_bfloat16 Bs[BN * BK];

    const int tid  = threadIdx.x;
    const int lane = tid & 63;
    const int wv   = tid >> 6;             // wave 0..3
    const int wr   = wv >> 1, wc = wv & 1; // 2x2 waves -> 64x64 each

    // XCD-aware bijective swizzle (all grids here are %8==0)
    int b = blockIdx.x;
    const int nwg = gridDim.x;
    if ((nwg & 7) == 0) {
        const int q = nwg >> 3;
        b = (b & 7) * q + (b >> 3);
    }
    const int nbx = Ng / BN;
    const int bx = b % nbx, by = b / nbx;
    const int row0 = by * BM, col0 = bx * BN;

    f32x4 acc[4][4] = {};

    const int frow = lane & 15;           // fragment row within 16
    const int fk   = (lane >> 4) * 8;     // fragment k offset within 32

    for (int k0 = 0; k0 < K; k0 += BK) {
        // --- stage A,B tiles: 128x64 bf16 each = 1024 16B-chunks = 256 thr x 4 it
        const int cwave = wv * 64;
        #pragma unroll
        for (int it = 0; it < 4; ++it) {
            const int chunkW = it * 256 + cwave;   // wave-uniform chunk base
            const int chunk  = chunkW + lane;      // this lane's chunk
            const int r = chunk >> 3;              // 8 chunks per 64-col row
            const int c = (chunk & 7) * 8;
            gload_lds16(A + (size_t)(row0 + r) * K + k0 + c, (void*)(As + chunkW * 8));
            gload_lds16(B + (size_t)(col0 + r) * K + k0 + c, (void*)(Bs + chunkW * 8));
        }
        __syncthreads();

        #pragma unroll
        for (int kk = 0; kk < 2; ++kk) {
            bf16x8 af[4], bfr[4];
            #pragma unroll
            for (int m = 0; m < 4; ++m)
                af[m] = *reinterpret_cast<const bf16x8*>(
                    &As[(wr * 64 + m * 16 + frow) * BK + kk * 32 + fk]);
            #pragma unroll
            for (int n = 0; n < 4; ++n)
                bfr[n] = *reinterpret_cast<const bf16x8*>(
                    &Bs[(wc * 64 + n * 16 + frow) * BK + kk * 32 + fk]);
            #pragma unroll
            for (int m = 0; m < 4; ++m)
                #pragma unroll
                for (int n = 0; n < 4; ++n)
                    acc[m][n] = __builtin_amdgcn_mfma_f32_16x16x32_bf16(
                        af[m], bfr[n], acc[m][n], 0, 0, 0);
        }
        __syncthreads();
    }

    // --- epilogue ---
    const int rbase  = row0 + wr * 64 + (lane >> 4) * 4;  // C row: rbase + m*16 + i
    const int cbase2 = col0 + wc * 64 + (lane & 15);      // C col: cbase2 + n*16
    #pragma unroll
    for (int m = 0; m < 4; ++m) {
        #pragma unroll
        for (int n = 0; n < 4; ++n) {
            const int col = cbase2 + n * 16;
            if constexpr (EPI == 3) {
                u16x4 pk;
                #pragma unroll
                for (int i = 0; i < 4; ++i) pk[i] = f2bf(acc[m][n][i]);
                *reinterpret_cast<u16x4*>(&outB[(size_t)col * ldT + rbase + m * 16]) = pk;
            } else {
                #pragma unroll
                for (int i = 0; i < 4; ++i) {
                    const int row = rbase + m * 16 + i;
                    const size_t idx = (size_t)row * Ng + col;
                    if constexpr (EPI == 1) {
                        float a = adj[idx];
                        float v = (row == col) ? a : acc[m][n][i] * a;
                        outB[idx] = __float2bfloat16(v);
                    } else {
                        outF[idx] = acc[m][n][i] + bias[col];
                    }
                }
            }
        }
    }
}

// ---------------------------------------------------------------------------
extern "C" void kernel_launch(void* const* d_in, const int* in_sizes, int n_in,
                              void* d_out, int out_size, void* d_ws, size_t ws_size,
                              hipStream_t stream) {
    const float* H_v  = (const float*)d_in[0];
    const float* ef   = (const float*)d_in[1];
    const float* adj  = (const float*)d_in[2];
    const float* T    = (const float*)d_in[3];
    const float* Wght = (const float*)d_in[4];
    const float* bias = (const float*)d_in[5];
    const float* p    = (const float*)d_in[6];
    float* out = (float*)d_out;

    const int dout = in_sizes[5];
    const int din  = in_sizes[4] / dout;
    const int N    = in_sizes[0] / din;
    const int E    = in_sizes[1] / 3;

    auto align256 = [](size_t x) { return (x + 255) & ~(size_t)255; };
    size_t off = 0;
    size_t off_w    = off; off = align256(off + (size_t)E * 4);
    size_t off_A    = off; off = align256(off + (size_t)N * E * 2);
    size_t off_B    = off; off = align256(off + (size_t)N * E * 2);
    size_t off_adjA = off; off = align256(off + (size_t)N * N * 2);
    size_t off_Hb   = off; off = align256(off + (size_t)N * din * 2);
    size_t off_Wt   = off; off = align256(off + (size_t)din * dout * 2);
    size_t off_HWt  = off; off = align256(off + (size_t)dout * N * 2);
    if (ws_size < off) return;  // workspace too small -> leave output poisoned (visible failure)

    char* ws = (char*)d_ws;
    float* w_f = (float*)(ws + off_w);
    __hip_bfloat16* Aw   = (__hip_bfloat16*)(ws + off_A);
    __hip_bfloat16* Bt   = (__hip_bfloat16*)(ws + off_B);
    __hip_bfloat16* adjA = (__hip_bfloat16*)(ws + off_adjA);
    __hip_bfloat16* Hb   = (__hip_bfloat16*)(ws + off_Hb);
    __hip_bfloat16* Wt   = (__hip_bfloat16*)(ws + off_Wt);
    __hip_bfloat16* HWt  = (__hip_bfloat16*)(ws + off_HWt);

    const unsigned int emask = ((E & (E - 1)) == 0) ? (unsigned int)(E - 1) : 0xFFFFFFFFu;

    // 1) per-edge weights
    calc_w<<<(E + 255) / 256, 256, 0, stream>>>(ef, p, w_f, E);
    // 2) T -> bf16 (scaled + plain)
    conv_T<<<2048, 256, 0, stream>>>(T, w_f, Aw, Bt, (size_t)N * E / 4, E, emask);
    // 3) H, W^T -> bf16
    conv_plain<<<1024, 256, 0, stream>>>(H_v, Hb, (size_t)N * din / 4);
    conv_Wt<<<(din * dout + 255) / 256, 256, 0, stream>>>(Wght, Wt, din, dout);
    // 4) HWt = (H @ W)^T   [dout][N] bf16
    gemm_bt<3><<<(N / 128) * (dout / 128), 256, 0, stream>>>(
        Hb, Wt, N, dout, din, nullptr, nullptr, nullptr, HWt, N);
    // 5) adjA = (diag-fixed multiplier) .* adj   [N][N] bf16
    gemm_bt<1><<<(N / 128) * (N / 128), 256, 0, stream>>>(
        Aw, Bt, N, N, E, adj, nullptr, nullptr, adjA, 0);
    // 6) out = adjA @ HW + bias   [N][dout] f32
    gemm_bt<2><<<(N / 128) * (dout / 128), 256, 0, stream>>>(
        adjA, HWt, N, dout, N, nullptr, out, bias, nullptr, 0);
}

// Round 4
// 1250.164 us; speedup vs baseline: 1.1427x; 1.1427x over previous
//
#include <hip/hip_runtime.h>
#include <hip/hip_bf16.h>
#include <stdint.h>

typedef __attribute__((ext_vector_type(4))) float f32x4;
typedef __attribute__((ext_vector_type(8))) short bf16x8;
typedef __attribute__((ext_vector_type(4))) unsigned short u16x4;

static __device__ __forceinline__ unsigned short f2bf(float f) {
    __hip_bfloat16 h = __float2bfloat16(f);
    return *reinterpret_cast<unsigned short*>(&h);
}

static __device__ __forceinline__ void gload_lds16(const void* g, void* l) {
    __builtin_amdgcn_global_load_lds(
        (const __attribute__((address_space(1))) unsigned int*)(uintptr_t)g,
        (__attribute__((address_space(3))) unsigned int*)(uintptr_t)l,
        16, 0, 0);
}

// ---------------------------------------------------------------------------
__global__ void calc_w(const float* __restrict__ ef, const float* __restrict__ p,
                       float* __restrict__ w, int E) {
    int e = blockIdx.x * 256 + threadIdx.x;
    if (e < E) w[e] = ef[3*e] * p[0] + ef[3*e+1] * p[1] + ef[3*e+2] * p[2];
}

__global__ void conv_T(const float* __restrict__ T, const float* __restrict__ wbuf,
                       __hip_bfloat16* __restrict__ Aw, __hip_bfloat16* __restrict__ Bt,
                       size_t total4, int E, unsigned int emask) {
    size_t i = (size_t)blockIdx.x * blockDim.x + threadIdx.x;
    size_t stride = (size_t)gridDim.x * blockDim.x;
    for (; i < total4; i += stride) {
        size_t base = i * 4;
        float4 t = reinterpret_cast<const float4*>(T)[i];
        int c = (emask != 0xFFFFFFFFu) ? (int)(base & (size_t)emask)
                                       : (int)(base % (size_t)E);
        float w0 = wbuf[c], w1 = wbuf[c+1], w2 = wbuf[c+2], w3 = wbuf[c+3];
        u16x4 b, a;
        b[0] = f2bf(t.x); b[1] = f2bf(t.y); b[2] = f2bf(t.z); b[3] = f2bf(t.w);
        a[0] = f2bf(t.x * w0); a[1] = f2bf(t.y * w1); a[2] = f2bf(t.z * w2); a[3] = f2bf(t.w * w3);
        reinterpret_cast<u16x4*>(Bt)[i] = b;
        reinterpret_cast<u16x4*>(Aw)[i] = a;
    }
}

__global__ void conv_plain(const float* __restrict__ src, __hip_bfloat16* __restrict__ dst,
                           size_t total4) {
    size_t i = (size_t)blockIdx.x * blockDim.x + threadIdx.x;
    size_t stride = (size_t)gridDim.x * blockDim.x;
    for (; i < total4; i += stride) {
        float4 t = reinterpret_cast<const float4*>(src)[i];
        u16x4 b;
        b[0] = f2bf(t.x); b[1] = f2bf(t.y); b[2] = f2bf(t.z); b[3] = f2bf(t.w);
        reinterpret_cast<u16x4*>(dst)[i] = b;
    }
}

__global__ void conv_Wt(const float* __restrict__ Wsrc, __hip_bfloat16* __restrict__ Wt,
                        int din, int dout) {
    int idx = blockIdx.x * 256 + threadIdx.x;
    if (idx < din * dout) {
        int i = idx / dout, j = idx % dout;
        Wt[(size_t)j * din + i] = __float2bfloat16(Wsrc[idx]);
    }
}

// ---------------------------------------------------------------------------
// C[M][Ng] = A[M][K] @ B[Ng][K]^T  (row-major, K contiguous; bf16 in, f32 acc)
// 128x128 tile, BK=64, 4 waves, 16x16x32 MFMA.
// + LDS double-buffer with early STAGE issue (T3-minimum: stage(t+1) before compute(t))
// + XOR bank-swizzle, both-sides (rule #21): linear LDS dest for global_load_lds,
//   pre-swizzled GLOBAL source col-chunk, same XOR applied on ds_read address.
//   granule(row, j) = row*8 + (j ^ (row&7))  -> each 4-bank group serves 8 distinct
//   granules = the 8-clock wave64 b128 floor (conflict-free).
template <int EPI>
__global__ __launch_bounds__(256)
void gemm_bt(const __hip_bfloat16* __restrict__ A, const __hip_bfloat16* __restrict__ B,
             int M, int Ng, int K,
             const float* __restrict__ adj, float* __restrict__ outF,
             const float* __restrict__ bias, __hip_bfloat16* __restrict__ outB, int ldT) {
    constexpr int BM = 128, BN = 128, BK = 64;
    __shared__ __align__(16) __hip_bfloat16 As[2][BM * BK];
    __shared__ __align__(16) __hip_bfloat16 Bs[2][BN * BK];

    const int tid  = threadIdx.x;
    const int lane = tid & 63;
    const int wv   = tid >> 6;             // wave 0..3
    const int wr   = wv >> 1, wc = wv & 1; // 2x2 waves -> 64x64 each

    // XCD-aware bijective swizzle (all grids here are %8==0)
    int b = blockIdx.x;
    const int nwg = gridDim.x;
    if ((nwg & 7) == 0) {
        const int q = nwg >> 3;
        b = (b & 7) * q + (b >> 3);
    }
    const int nbx = Ng / BN;
    const int bx = b % nbx, by = b / nbx;
    const int row0 = by * BM, col0 = bx * BN;

    f32x4 acc[4][4] = {};

    const int frow = lane & 15;           // fragment row within 16
    const int hi   = lane >> 4;           // k-subchunk 0..3
    const int r7   = frow & 7;            // row mod 8 (same for all frag rows)

    // staging geometry (per 16B chunk): chunk = it*256 + wv*64 + lane
    //   r = chunk>>3 (tile row), jj = chunk&7 (LDS col-chunk)
    //   global col-chunk = jj ^ (r&7)  (inverse-swizzled source)
    const int NT = K / BK;

    auto stage = [&](int t, int bufi) {
        const int k0 = t * BK;
        #pragma unroll
        for (int it = 0; it < 4; ++it) {
            const int chunkW = it * 256 + wv * 64;   // wave-uniform chunk base
            const int chunk  = chunkW + lane;
            const int r  = chunk >> 3;
            const int jj = chunk & 7;
            const int c  = (jj ^ (r & 7)) * 8;       // swizzled source col (elements)
            gload_lds16(A + (size_t)(row0 + r) * K + k0 + c, (void*)(&As[bufi][chunkW * 8]));
            gload_lds16(B + (size_t)(col0 + r) * K + k0 + c, (void*)(&Bs[bufi][chunkW * 8]));
        }
    };

    stage(0, 0);
    __syncthreads();

    for (int t = 0; t < NT; ++t) {
        if (t + 1 < NT) stage(t + 1, (t + 1) & 1);   // issue async prefetch first
        const int bufi = t & 1;
        #pragma unroll
        for (int kk = 0; kk < 2; ++kk) {
            // swizzled col offset (elements), identical for A and B (row&7 == r7)
            const int co = ((kk * 4 + hi) ^ r7) * 8;
            bf16x8 af[4], bfr[4];
            #pragma unroll
            for (int m = 0; m < 4; ++m)
                af[m] = *reinterpret_cast<const bf16x8*>(
                    &As[bufi][(wr * 64 + m * 16 + frow) * BK + co]);
            #pragma unroll
            for (int n = 0; n < 4; ++n)
                bfr[n] = *reinterpret_cast<const bf16x8*>(
                    &Bs[bufi][(wc * 64 + n * 16 + frow) * BK + co]);
            #pragma unroll
            for (int m = 0; m < 4; ++m)
                #pragma unroll
                for (int n = 0; n < 4; ++n)
                    acc[m][n] = __builtin_amdgcn_mfma_f32_16x16x32_bf16(
                        af[m], bfr[n], acc[m][n], 0, 0, 0);
        }
        __syncthreads();   // drains vmcnt(0)+lgkmcnt(0): prefetch landed, reads done
    }

    // --- epilogue ---
    const int rbase  = row0 + wr * 64 + (lane >> 4) * 4;  // C row: rbase + m*16 + i
    const int cbase2 = col0 + wc * 64 + (lane & 15);      // C col: cbase2 + n*16
    #pragma unroll
    for (int m = 0; m < 4; ++m) {
        #pragma unroll
        for (int n = 0; n < 4; ++n) {
            const int col = cbase2 + n * 16;
            if constexpr (EPI == 3) {
                u16x4 pk;
                #pragma unroll
                for (int i = 0; i < 4; ++i) pk[i] = f2bf(acc[m][n][i]);
                *reinterpret_cast<u16x4*>(&outB[(size_t)col * ldT + rbase + m * 16]) = pk;
            } else {
                #pragma unroll
                for (int i = 0; i < 4; ++i) {
                    const int row = rbase + m * 16 + i;
                    const size_t idx = (size_t)row * Ng + col;
                    if constexpr (EPI == 1) {
                        float a = adj[idx];
                        float v = (row == col) ? a : acc[m][n][i] * a;
                        outB[idx] = __float2bfloat16(v);
                    } else {
                        outF[idx] = acc[m][n][i] + bias[col];
                    }
                }
            }
        }
    }
}

// ---------------------------------------------------------------------------
extern "C" void kernel_launch(void* const* d_in, const int* in_sizes, int n_in,
                              void* d_out, int out_size, void* d_ws, size_t ws_size,
                              hipStream_t stream) {
    const float* H_v  = (const float*)d_in[0];
    const float* ef   = (const float*)d_in[1];
    const float* adj  = (const float*)d_in[2];
    const float* T    = (const float*)d_in[3];
    const float* Wght = (const float*)d_in[4];
    const float* bias = (const float*)d_in[5];
    const float* p    = (const float*)d_in[6];
    float* out = (float*)d_out;

    const int dout = in_sizes[5];
    const int din  = in_sizes[4] / dout;
    const int N    = in_sizes[0] / din;
    const int E    = in_sizes[1] / 3;

    auto align256 = [](size_t x) { return (x + 255) & ~(size_t)255; };
    size_t off = 0;
    size_t off_w    = off; off = align256(off + (size_t)E * 4);
    size_t off_A    = off; off = align256(off + (size_t)N * E * 2);
    size_t off_B    = off; off = align256(off + (size_t)N * E * 2);
    size_t off_adjA = off; off = align256(off + (size_t)N * N * 2);
    size_t off_Hb   = off; off = align256(off + (size_t)N * din * 2);
    size_t off_Wt   = off; off = align256(off + (size_t)din * dout * 2);
    size_t off_HWt  = off; off = align256(off + (size_t)dout * N * 2);
    if (ws_size < off) return;  // workspace too small -> visible failure

    char* ws = (char*)d_ws;
    float* w_f = (float*)(ws + off_w);
    __hip_bfloat16* Aw   = (__hip_bfloat16*)(ws + off_A);
    __hip_bfloat16* Bt   = (__hip_bfloat16*)(ws + off_B);
    __hip_bfloat16* adjA = (__hip_bfloat16*)(ws + off_adjA);
    __hip_bfloat16* Hb   = (__hip_bfloat16*)(ws + off_Hb);
    __hip_bfloat16* Wt   = (__hip_bfloat16*)(ws + off_Wt);
    __hip_bfloat16* HWt  = (__hip_bfloat16*)(ws + off_HWt);

    const unsigned int emask = ((E & (E - 1)) == 0) ? (unsigned int)(E - 1) : 0xFFFFFFFFu;

    calc_w<<<(E + 255) / 256, 256, 0, stream>>>(ef, p, w_f, E);
    conv_T<<<2048, 256, 0, stream>>>(T, w_f, Aw, Bt, (size_t)N * E / 4, E, emask);
    conv_plain<<<1024, 256, 0, stream>>>(H_v, Hb, (size_t)N * din / 4);
    conv_Wt<<<(din * dout + 255) / 256, 256, 0, stream>>>(Wght, Wt, din, dout);
    // HWt = (H @ W)^T   [dout][N] bf16
    gemm_bt<3><<<(N / 128) * (dout / 128), 256, 0, stream>>>(
        Hb, Wt, N, dout, din, nullptr, nullptr, nullptr, HWt, N);
    // adjA = (diag-fixed multiplier) .* adj   [N][N] bf16
    gemm_bt<1><<<(N / 128) * (N / 128), 256, 0, stream>>>(
        Aw, Bt, N, N, E, adj, nullptr, nullptr, adjA, 0);
    // out = adjA @ HW + bias   [N][dout] f32
    gemm_bt<2><<<(N / 128) * (dout / 128), 256, 0, stream>>>(
        adjA, HWt, N, dout, N, nullptr, out, bias, nullptr, 0);
}

// Round 9
// 1020.306 us; speedup vs baseline: 1.4001x; 1.2253x over previous
//
#include <hip/hip_runtime.h>
#include <hip/hip_bf16.h>
#include <stdint.h>

typedef __attribute__((ext_vector_type(4))) float f32x4;
typedef __attribute__((ext_vector_type(8))) short bf16x8;
typedef __attribute__((ext_vector_type(4))) unsigned short u16x4;

static __device__ __forceinline__ unsigned short f2bf(float f) {
    __hip_bfloat16 h = __float2bfloat16(f);
    return *reinterpret_cast<unsigned short*>(&h);
}

static __device__ __forceinline__ void gload_lds16(const void* g, void* l) {
    __builtin_amdgcn_global_load_lds(
        (const __attribute__((address_space(1))) unsigned int*)(uintptr_t)g,
        (__attribute__((address_space(3))) unsigned int*)(uintptr_t)l,
        16, 0, 0);
}

// ---------------------------------------------------------------------------
__global__ void calc_w(const float* __restrict__ ef, const float* __restrict__ p,
                       float* __restrict__ w, int E) {
    int e = blockIdx.x * 256 + threadIdx.x;
    if (e < E) w[e] = ef[3*e] * p[0] + ef[3*e+1] * p[1] + ef[3*e+2] * p[2];
}

__global__ void conv_T(const float* __restrict__ T, const float* __restrict__ wbuf,
                       __hip_bfloat16* __restrict__ Aw, __hip_bfloat16* __restrict__ Bt,
                       size_t total4, int E, unsigned int emask) {
    size_t i = (size_t)blockIdx.x * blockDim.x + threadIdx.x;
    size_t stride = (size_t)gridDim.x * blockDim.x;
    for (; i < total4; i += stride) {
        size_t base = i * 4;
        float4 t = reinterpret_cast<const float4*>(T)[i];
        int c = (emask != 0xFFFFFFFFu) ? (int)(base & (size_t)emask)
                                       : (int)(base % (size_t)E);
        float w0 = wbuf[c], w1 = wbuf[c+1], w2 = wbuf[c+2], w3 = wbuf[c+3];
        u16x4 b, a;
        b[0] = f2bf(t.x); b[1] = f2bf(t.y); b[2] = f2bf(t.z); b[3] = f2bf(t.w);
        a[0] = f2bf(t.x * w0); a[1] = f2bf(t.y * w1); a[2] = f2bf(t.z * w2); a[3] = f2bf(t.w * w3);
        reinterpret_cast<u16x4*>(Bt)[i] = b;
        reinterpret_cast<u16x4*>(Aw)[i] = a;
    }
}

__global__ void conv_plain(const float* __restrict__ src, __hip_bfloat16* __restrict__ dst,
                           size_t total4) {
    size_t i = (size_t)blockIdx.x * blockDim.x + threadIdx.x;
    size_t stride = (size_t)gridDim.x * blockDim.x;
    for (; i < total4; i += stride) {
        float4 t = reinterpret_cast<const float4*>(src)[i];
        u16x4 b;
        b[0] = f2bf(t.x); b[1] = f2bf(t.y); b[2] = f2bf(t.z); b[3] = f2bf(t.w);
        reinterpret_cast<u16x4*>(dst)[i] = b;
    }
}

__global__ void conv_Wt(const float* __restrict__ Wsrc, __hip_bfloat16* __restrict__ Wt,
                        int din, int dout) {
    int idx = blockIdx.x * 256 + threadIdx.x;
    if (idx < din * dout) {
        int i = idx / dout, j = idx % dout;
        Wt[(size_t)j * din + i] = __float2bfloat16(Wsrc[idx]);
    }
}

// ---------------------------------------------------------------------------
// 128x128-tile 2-phase GEMM — HW-VERIFIED (round-4 bench: passed, conflicts=0,
// 745us on the NxN GEMM). Used for the small GEMMs (full CU coverage at 256 WGs).
// C[M][Ng] = A[M][K] @ B[Ng][K]^T; EPI semantics as below.
template <int EPI>
__global__ __launch_bounds__(256)
void gemm_bt(const __hip_bfloat16* __restrict__ A, const __hip_bfloat16* __restrict__ B,
             int M, int Ng, int K,
             const float* __restrict__ adj, float* __restrict__ outF,
             const float* __restrict__ bias, __hip_bfloat16* __restrict__ outB, int ldT) {
    constexpr int BM = 128, BN = 128, BK = 64;
    __shared__ __align__(16) __hip_bfloat16 As[2][BM * BK];
    __shared__ __align__(16) __hip_bfloat16 Bs[2][BN * BK];

    const int tid  = threadIdx.x;
    const int lane = tid & 63;
    const int wv   = tid >> 6;
    const int wr   = wv >> 1, wc = wv & 1;

    int b = blockIdx.x;
    const int nwg = gridDim.x;
    if ((nwg & 7) == 0) {
        const int q = nwg >> 3;
        b = (b & 7) * q + (b >> 3);
    }
    const int nbx = Ng / BN;
    const int bx = b % nbx, by = b / nbx;
    const int row0 = by * BM, col0 = bx * BN;

    f32x4 acc[4][4] = {};

    const int frow = lane & 15;
    const int hi   = lane >> 4;
    const int r7   = frow & 7;
    const int NT   = K / BK;

    auto stage = [&](int t, int bufi) {
        const int k0 = t * BK;
        #pragma unroll
        for (int it = 0; it < 4; ++it) {
            const int chunkW = it * 256 + wv * 64;
            const int chunk  = chunkW + lane;
            const int r  = chunk >> 3;
            const int jj = chunk & 7;
            const int c  = (jj ^ (r & 7)) * 8;
            gload_lds16(A + (size_t)(row0 + r) * K + k0 + c, (void*)(&As[bufi][chunkW * 8]));
            gload_lds16(B + (size_t)(col0 + r) * K + k0 + c, (void*)(&Bs[bufi][chunkW * 8]));
        }
    };

    stage(0, 0);
    __syncthreads();

    for (int t = 0; t < NT; ++t) {
        if (t + 1 < NT) stage(t + 1, (t + 1) & 1);
        const int bufi = t & 1;
        #pragma unroll
        for (int kk = 0; kk < 2; ++kk) {
            const int co = ((kk * 4 + hi) ^ r7) * 8;
            bf16x8 af[4], bfr[4];
            #pragma unroll
            for (int m = 0; m < 4; ++m)
                af[m] = *reinterpret_cast<const bf16x8*>(
                    &As[bufi][(wr * 64 + m * 16 + frow) * BK + co]);
            #pragma unroll
            for (int n = 0; n < 4; ++n)
                bfr[n] = *reinterpret_cast<const bf16x8*>(
                    &Bs[bufi][(wc * 64 + n * 16 + frow) * BK + co]);
            #pragma unroll
            for (int m = 0; m < 4; ++m)
                #pragma unroll
                for (int n = 0; n < 4; ++n)
                    acc[m][n] = __builtin_amdgcn_mfma_f32_16x16x32_bf16(
                        af[m], bfr[n], acc[m][n], 0, 0, 0);
        }
        __syncthreads();
    }

    const int rbase  = row0 + wr * 64 + hi * 4;
    const int cbase2 = col0 + wc * 64 + frow;
    #pragma unroll
    for (int m = 0; m < 4; ++m) {
        #pragma unroll
        for (int n = 0; n < 4; ++n) {
            const int col = cbase2 + n * 16;
            if constexpr (EPI == 3) {
                u16x4 pk;
                #pragma unroll
                for (int i = 0; i < 4; ++i) pk[i] = f2bf(acc[m][n][i]);
                *reinterpret_cast<u16x4*>(&outB[(size_t)col * ldT + rbase + m * 16]) = pk;
            } else {
                #pragma unroll
                for (int i = 0; i < 4; ++i) {
                    const int row = rbase + m * 16 + i;
                    const size_t idx = (size_t)row * Ng + col;
                    if constexpr (EPI == 1) {
                        float a = adj[idx];
                        float v = (row == col) ? a : acc[m][n][i] * a;
                        outB[idx] = __float2bfloat16(v);
                    } else {
                        outF[idx] = acc[m][n][i] + bias[col];
                    }
                }
            }
        }
    }
}

// ---------------------------------------------------------------------------
// 256x256-tile, BK=64, 8 waves (2M x 4N), 8-phase schedule with counted vmcnt —
// used ONLY for the dominant NxN multiplier GEMM (256 WGs = full coverage).
//  - half-tile (128x64) staging via global_load_lds (linear LDS dest)
//  - XOR bank-swizzle both-sides (HW-verified: conflicts 2e8 -> 0)
//  - raw s_barrier + vmcnt(4) at tile boundary (never 0 in steady state)
//  - A-frags loaded at nh==0, register-reused at nh==1 (32 ds_read_b128/wave/tile)
// Pipeline invariants (hand-verified, 3 passes):
//  * stores into buf[d^1] issue only after the barrier following every wave's
//    lgkm-drained last read of buf[d^1].
//  * reads of tile t follow {vmcnt(4); barrier}: only t+1's 4 A-half loads in flight.
//  * last tile drains vmcnt(0).
template <int EPI>
__global__ __launch_bounds__(512)
void gemm8_bt(const __hip_bfloat16* __restrict__ A, const __hip_bfloat16* __restrict__ B,
              int M, int Ng, int K,
              const float* __restrict__ adj, float* __restrict__ outF,
              const float* __restrict__ bias, __hip_bfloat16* __restrict__ outB, int ldT) {
    constexpr int BM = 256, BN = 256, BK = 64;
    __shared__ __align__(16) __hip_bfloat16 As[2][2 * 8192];
    __shared__ __align__(16) __hip_bfloat16 Bs[2][2 * 8192];

    const int tid  = threadIdx.x;
    const int lane = tid & 63;
    const int wid  = tid >> 6;
    const int wr   = wid >> 2;
    const int wc   = wid & 3;

    int b = blockIdx.x;
    const int nwg = gridDim.x;
    if ((nwg & 7) == 0) {
        const int q = nwg >> 3;
        b = (b & 7) * q + (b >> 3);
    }
    const int nbx = Ng / BN;
    const int bx = b % nbx, by = b / nbx;
    const int row0 = by * BM, col0 = bx * BN;

    f32x4 acc[8][4] = {};

    const int frow = lane & 15;
    const int hi   = lane >> 4;
    const int r7   = frow & 7;
    const int NT   = K / BK;

    auto stage_half = [&](int t, int dbuf, int part) {
        const int k0 = t * BK;
        const __hip_bfloat16* src = (part < 2) ? A : B;
        const int base0 = (part < 2) ? row0 : col0;
        const int h = part & 1;
        __hip_bfloat16* dst = (part < 2) ? &As[dbuf][h * 8192] : &Bs[dbuf][h * 8192];
        #pragma unroll
        for (int it = 0; it < 2; ++it) {
            const int chunkW = it * 512 + (tid & ~63);
            const int chunk  = chunkW + lane;
            const int r  = chunk >> 3;
            const int jj = chunk & 7;
            const int c  = (jj ^ (r & 7)) * 8;
            gload_lds16(src + (size_t)(base0 + h * 128 + r) * K + k0 + c,
                        (void*)(dst + chunkW * 8));
        }
    };

    stage_half(0, 0, 0); stage_half(0, 0, 1); stage_half(0, 0, 2); stage_half(0, 0, 3);

    for (int t = 0; t < NT; ++t) {
        const int d = t & 1;
        if (t + 1 < NT) {
            stage_half(t + 1, d ^ 1, 0);
            stage_half(t + 1, d ^ 1, 1);
            asm volatile("s_waitcnt vmcnt(4)" ::: "memory");
        } else {
            asm volatile("s_waitcnt vmcnt(0)" ::: "memory");
        }
        __builtin_amdgcn_s_barrier();
        __builtin_amdgcn_sched_barrier(0);

        bf16x8 af[4][2];
        #pragma unroll
        for (int p = 0; p < 4; ++p) {
            const int mh = p >> 1, nh = p & 1;
            if (nh == 0) {
                #pragma unroll
                for (int mm = 0; mm < 4; ++mm)
                    #pragma unroll
                    for (int kk = 0; kk < 2; ++kk) {
                        const int row = (mh * 4 + mm) * 16 + frow;
                        const int co  = ((kk * 4 + hi) ^ r7) * 8;
                        af[mm][kk] = *reinterpret_cast<const bf16x8*>(
                            &As[d][wr * 8192 + row * 64 + co]);
                    }
            }
            bf16x8 bq[2][2];
            #pragma unroll
            for (int nn = 0; nn < 2; ++nn)
                #pragma unroll
                for (int kk = 0; kk < 2; ++kk) {
                    const int row = (wc & 1) * 64 + (nh * 2 + nn) * 16 + frow;
                    const int co  = ((kk * 4 + hi) ^ r7) * 8;
                    bq[nn][kk] = *reinterpret_cast<const bf16x8*>(
                        &Bs[d][(wc >> 1) * 8192 + row * 64 + co]);
                }
            if (p == 1 && t + 1 < NT) {
                stage_half(t + 1, d ^ 1, 2);
                stage_half(t + 1, d ^ 1, 3);
            }
            __builtin_amdgcn_s_barrier();
            asm volatile("s_waitcnt lgkmcnt(0)");
            __builtin_amdgcn_s_setprio(1);
            #pragma unroll
            for (int mm = 0; mm < 4; ++mm)
                #pragma unroll
                for (int nn = 0; nn < 2; ++nn)
                    #pragma unroll
                    for (int kk = 0; kk < 2; ++kk)
                        acc[mh * 4 + mm][nh * 2 + nn] =
                            __builtin_amdgcn_mfma_f32_16x16x32_bf16(
                                af[mm][kk], bq[nn][kk], acc[mh * 4 + mm][nh * 2 + nn], 0, 0, 0);
            __builtin_amdgcn_s_setprio(0);
            __builtin_amdgcn_s_barrier();
        }
    }

    const int rbase  = row0 + wr * 128 + hi * 4;
    const int cbase2 = col0 + wc * 64 + frow;
    #pragma unroll
    for (int m = 0; m < 8; ++m) {
        #pragma unroll
        for (int n = 0; n < 4; ++n) {
            const int col = cbase2 + n * 16;
            if constexpr (EPI == 3) {
                u16x4 pk;
                #pragma unroll
                for (int i = 0; i < 4; ++i) pk[i] = f2bf(acc[m][n][i]);
                *reinterpret_cast<u16x4*>(&outB[(size_t)col * ldT + rbase + m * 16]) = pk;
            } else {
                #pragma unroll
                for (int i = 0; i < 4; ++i) {
                    const int row = rbase + m * 16 + i;
                    const size_t idx = (size_t)row * Ng + col;
                    if constexpr (EPI == 1) {
                        float a = adj[idx];
                        float v = (row == col) ? a : acc[m][n][i] * a;
                        outB[idx] = __float2bfloat16(v);
                    } else {
                        outF[idx] = acc[m][n][i] + bias[col];
                    }
                }
            }
        }
    }
}

// ---------------------------------------------------------------------------
extern "C" void kernel_launch(void* const* d_in, const int* in_sizes, int n_in,
                              void* d_out, int out_size, void* d_ws, size_t ws_size,
                              hipStream_t stream) {
    const float* H_v  = (const float*)d_in[0];
    const float* ef   = (const float*)d_in[1];
    const float* adj  = (const float*)d_in[2];
    const float* T    = (const float*)d_in[3];
    const float* Wght = (const float*)d_in[4];
    const float* bias = (const float*)d_in[5];
    const float* p    = (const float*)d_in[6];
    float* out = (float*)d_out;

    const int dout = in_sizes[5];
    const int din  = in_sizes[4] / dout;
    const int N    = in_sizes[0] / din;
    const int E    = in_sizes[1] / 3;

    auto align256 = [](size_t x) { return (x + 255) & ~(size_t)255; };
    size_t off = 0;
    size_t off_w    = off; off = align256(off + (size_t)E * 4);
    size_t off_A    = off; off = align256(off + (size_t)N * E * 2);
    size_t off_B    = off; off = align256(off + (size_t)N * E * 2);
    size_t off_adjA = off; off = align256(off + (size_t)N * N * 2);
    size_t off_Hb   = off; off = align256(off + (size_t)N * din * 2);
    size_t off_Wt   = off; off = align256(off + (size_t)din * dout * 2);
    size_t off_HWt  = off; off = align256(off + (size_t)dout * N * 2);
    if (ws_size < off) return;  // workspace too small -> visible failure

    char* ws = (char*)d_ws;
    float* w_f = (float*)(ws + off_w);
    __hip_bfloat16* Aw   = (__hip_bfloat16*)(ws + off_A);
    __hip_bfloat16* Bt   = (__hip_bfloat16*)(ws + off_B);
    __hip_bfloat16* adjA = (__hip_bfloat16*)(ws + off_adjA);
    __hip_bfloat16* Hb   = (__hip_bfloat16*)(ws + off_Hb);
    __hip_bfloat16* Wt   = (__hip_bfloat16*)(ws + off_Wt);
    __hip_bfloat16* HWt  = (__hip_bfloat16*)(ws + off_HWt);

    const unsigned int emask = ((E & (E - 1)) == 0) ? (unsigned int)(E - 1) : 0xFFFFFFFFu;

    calc_w<<<(E + 255) / 256, 256, 0, stream>>>(ef, p, w_f, E);
    conv_T<<<2048, 256, 0, stream>>>(T, w_f, Aw, Bt, (size_t)N * E / 4, E, emask);
    conv_plain<<<1024, 256, 0, stream>>>(H_v, Hb, (size_t)N * din / 4);
    conv_Wt<<<(din * dout + 255) / 256, 256, 0, stream>>>(Wght, Wt, din, dout);
    // HWt = (H @ W)^T  [dout][N] bf16  — small GEMM: 128^2 tile for full CU coverage
    gemm_bt<3><<<(N / 128) * (dout / 128), 256, 0, stream>>>(
        Hb, Wt, N, dout, din, nullptr, nullptr, nullptr, HWt, N);
    // adjA = (diag-fixed multiplier) .* adj  [N][N] bf16 — dominant GEMM: 8-phase 256^2
    gemm8_bt<1><<<(N / 256) * (N / 256), 512, 0, stream>>>(
        Aw, Bt, N, N, E, adj, nullptr, nullptr, adjA, 0);
    // out = adjA @ HW + bias  [N][dout] f32 — small GEMM: 128^2 tile
    gemm_bt<2><<<(N / 128) * (dout / 128), 256, 0, stream>>>(
        adjA, HWt, N, dout, N, nullptr, out, bias, nullptr, 0);
}